// Round 1
// 1420.303 us; speedup vs baseline: 1.2001x; 1.2001x over previous
//
#include <hip/hip_runtime.h>
#include <hip/hip_bf16.h>

typedef unsigned short u16;
typedef unsigned int   u32;
typedef __bf16 bf16x8 __attribute__((ext_vector_type(8)));
typedef float  f32x4  __attribute__((ext_vector_type(4)));

#define AS1 __attribute__((address_space(1)))
#define AS3 __attribute__((address_space(3)))

__device__ __forceinline__ u16 f2bf(float f){
    u32 u = __float_as_uint(f);
    u32 r = u + 0x7fffu + ((u>>16)&1u);
    return (u16)(r>>16);
}
__device__ __forceinline__ float bf2f(u16 u){ return __uint_as_float(((u32)u)<<16); }

// ---------------- degree ----------------
__global__ void k_deg(const int* __restrict__ dst, float* __restrict__ degb, int E){
    int e = blockIdx.x*256 + threadIdx.x;
    if (e < E) atomicAdd(&degb[dst[e]], 1.0f);
}

// degb -> invdeg in place; rw0 = degc^2 (so rw0*invdeg = degc = RWSE col 0)
__global__ void k_degc(float* __restrict__ invdeg, float* __restrict__ rw0, int n){
    int v = blockIdx.x*256 + threadIdx.x;
    if (v < n){
        float c = invdeg[v];
        if (c == 0.f) c = 1.f;
        invdeg[v] = 1.f/c;
        rw0[v] = c*c;
    }
}

// raw_{t+1}[dst] += (raw_t[src] * invdeg[src])
__global__ void k_rwse(const float* __restrict__ cur, float* __restrict__ nxt,
                       const float* __restrict__ invdeg, const int* __restrict__ src,
                       const int* __restrict__ dst, int E){
    int e = blockIdx.x*256 + threadIdx.x;
    if (e < E){
        int s = src[e];
        atomicAdd(&nxt[dst[e]], cur[s]*invdeg[s]);
    }
}

// out0 = relu([n_feat, rwse] @ lin0_w + lin0_b)   (fp32)
__global__ void k_finalize(const float* __restrict__ nfeat, const float* __restrict__ rw,
                           const float* __restrict__ invdeg,
                           const float* __restrict__ lw, const float* __restrict__ lb,
                           float* __restrict__ out0, int n){
    __shared__ float lwl[1024];
    __shared__ float lbl[32];
    __shared__ float nfl[8][32];
    int tid = threadIdx.x;
    for (int i = tid; i < 1024; i += 256) lwl[i] = lw[i];
    if (tid < 32) lbl[tid] = lb[tid];
    int slot = tid>>5, o = tid&31;
    int v = blockIdx.x*8 + slot;
    float nfv = 0.f;
    if (v < n){
        nfv = (o < 16) ? nfeat[(size_t)v*16 + o]
                       : rw[(size_t)(o-16)*n + v]*invdeg[v];
    }
    nfl[slot][o] = nfv;
    __syncthreads();
    if (v < n){
        float a = lbl[o];
        #pragma unroll
        for (int j = 0; j < 32; j++) a += nfl[slot][j]*lwl[j*32+o];
        out0[(size_t)v*32 + o] = a > 0.f ? a : 0.f;
    }
}

// WT[n*1024+k] = bf16(w[k*1024+n])  (fp32 -> bf16, 1024x1024)
__global__ void k_transpose(const float* __restrict__ w, u16* __restrict__ wt){
    __shared__ float t[32][33];
    int bx = blockIdx.x & 31, by = blockIdx.x >> 5;
    int x = threadIdx.x & 31, y = threadIdx.x >> 5;
    #pragma unroll
    for (int i = 0; i < 32; i += 8)
        t[y+i][x] = w[(size_t)(by*32 + y + i)*1024 + bx*32 + x];
    __syncthreads();
    #pragma unroll
    for (int i = 0; i < 32; i += 8)
        wt[(size_t)(bx*32 + y + i)*1024 + by*32 + x] = f2bf(t[x][y+i]);
}

// Pre-pass: A fp32 -> bf16 (rounded), plus gate[e] = sigmoid(A[e,:] . gw + gb) in fp32.
// One wave per row; memory-bound streaming (410 MB read + 205 MB write).
__global__ __launch_bounds__(256) void k_prep(
    const float* __restrict__ A, const float* __restrict__ gw,
    const float* __restrict__ gb, u16* __restrict__ Abf,
    float* __restrict__ gate, int E)
{
    __shared__ f32x4 gwl[256];
    const int tid = threadIdx.x;
    const int wave = tid>>6, lane = tid&63;
    gwl[tid] = ((const f32x4*)gw)[tid];
    __syncthreads();
    const int row = blockIdx.x*4 + wave;
    if (row >= E) return;
    const f32x4* ar = (const f32x4*)(A + (size_t)row*1024);
    ushort4* br = (ushort4*)(Abf + (size_t)row*1024);
    float g = 0.f;
    #pragma unroll
    for (int j = 0; j < 4; j++){
        const int idx = j*64 + lane;
        f32x4 v = ar[idx];
        f32x4 w4 = gwl[idx];
        g += v.x*w4.x + v.y*w4.y + v.z*w4.z + v.w*w4.w;
        ushort4 o;
        o.x = f2bf(v.x); o.y = f2bf(v.y); o.z = f2bf(v.z); o.w = f2bf(v.w);
        br[idx] = o;
    }
    #pragma unroll
    for (int m = 32; m >= 1; m >>= 1) g += __shfl_xor(g, m);
    if (lane == 0) gate[row] = 1.f/(1.f + __expf(-(g + gb[0])));
}

// W = relu(A @ B + bias) * gate, natural row-major store [h*32+o].
// Clean m97 structure: A bf16 (pre-converted), B bf16 (pre-transposed),
// per K-step per lane: 4x global_load_lds(16B) + 8x ds_read_b128 + 16x MFMA.
// Grid swizzled so the 8 column-sibling blocks of one row panel share an XCD/L2.
__global__ __launch_bounds__(256) void k_gemm(
    const u16* __restrict__ A, const u16* __restrict__ BT,
    const float* __restrict__ bias, const float* __restrict__ gate,
    u16* __restrict__ Wout, int E)
{
    __shared__ __align__(16) u16 lds_a[128*32];  // [q][m] chunks of 8 bf16
    __shared__ __align__(16) u16 lds_b[128*32];  // [q][n] chunks of 8 bf16
    __shared__ float gate_lds[128];
    __shared__ float bias_lds[128];

    const int tid  = threadIdx.x;
    const int wave = tid>>6, lane = tid&63;
    const int wm = wave>>1, wn = wave&1;
    const int ql = lane>>4, rl = lane&15;

    // swizzle: 8 nb-siblings of a row panel sit at ids == same value mod 8
    const int id  = blockIdx.x;
    const int xcd = id & 7;
    const int s   = id >> 3;
    const int nb  = s & 7;
    const int mb  = (s >> 3)*8 + xcd;
    const int MBtot = (E + 127) >> 7;
    if (mb >= MBtot) return;
    const int m0 = mb<<7, n0 = nb<<7;

    if (tid < 128){
        const int row = m0 + tid;
        gate_lds[tid] = gate[row < E ? row : E-1];
    } else {
        bias_lds[tid-128] = bias[n0 + tid - 128];
    }

    f32x4 acc[4][4];
    #pragma unroll
    for (int i=0;i<4;i++)
    #pragma unroll
        for (int j=0;j<4;j++) acc[i][j] = (f32x4){0.f,0.f,0.f,0.f};

    for (int k0 = 0; k0 < 1024; k0 += 32){
        __syncthreads();
        // A and B: each 512 chunks of 16B; ci -> (m|n = ci&127, q = ci>>7)
        #pragma unroll
        for (int j=0;j<2;j++){
            const int cb = (j*4 + wave)*64;        // wave-uniform
            const int ci = cb + lane;
            const int m  = ci & 127, q = ci >> 7;
            int row = m0 + m; if (row >= E) row = E-1;
            const u16* ga = A + (size_t)row*1024 + k0 + q*8;
            __builtin_amdgcn_global_load_lds(
                (const AS1 void*)ga, (AS3 void*)&lds_a[ci*8], 16, 0, 0);
            const u16* gB = BT + (size_t)(n0 + m)*1024 + (k0 + q*8);
            __builtin_amdgcn_global_load_lds(
                (const AS1 void*)gB, (AS3 void*)&lds_b[ci*8], 16, 0, 0);
        }
        __syncthreads();

        bf16x8 af[4], bfr[4];
        #pragma unroll
        for (int t=0;t<4;t++){
            af[t]  = *(const bf16x8*)&lds_a[(ql*128 + wm*64 + t*16 + rl)*8];
            bfr[t] = *(const bf16x8*)&lds_b[(ql*128 + wn*64 + t*16 + rl)*8];
        }
        #pragma unroll
        for (int mt=0;mt<4;mt++)
        #pragma unroll
            for (int nt=0;nt<4;nt++)
                acc[mt][nt] = __builtin_amdgcn_mfma_f32_16x16x32_bf16(af[mt], bfr[nt], acc[mt][nt], 0,0,0);
    }

    float bcol[4];
    #pragma unroll
    for (int nt=0;nt<4;nt++) bcol[nt] = bias_lds[wn*64 + nt*16 + rl];

    #pragma unroll
    for (int mt=0;mt<4;mt++){
        const int rloc0 = wm*64 + mt*16 + ql*4;
        #pragma unroll
        for (int r=0;r<4;r++){
            const int row = m0 + rloc0 + r;
            if (row < E){
                const float g = gate_lds[rloc0 + r];
                u16* wrow = Wout + (size_t)row*1024 + n0 + wn*64 + rl;
                #pragma unroll
                for (int nt=0;nt<4;nt++){    // consecutive nt -> adjacent 32B runs, write-combine
                    float v = acc[mt][nt][r] + bcol[nt];
                    v = v > 0.f ? v : 0.f;
                    wrow[nt*16] = f2bf(v*g);
                }
            }
        }
    }
}

// msg[e][o] = sum_h out[src[e]][h] * W[e, h*32+o]; atomic into neigh[dst]
__global__ void k_msg(const float* __restrict__ outc, const u16* __restrict__ W,
                      const int* __restrict__ src, const int* __restrict__ dst,
                      float* __restrict__ neigh, int E)
{
    __shared__ float xl[8][32];
    const int tid = threadIdx.x, slot = tid>>5, o = tid&31;
    const int e = blockIdx.x*8 + slot;
    int d = 0;
    if (e < E){
        d = dst[e];
        xl[slot][o] = outc[(size_t)src[e]*32 + o];
    }
    __syncthreads();
    if (e < E){
        const float* x = xl[slot];
        const u16* wr = W + (size_t)e*1024 + o;
        float acc = 0.f;
        #pragma unroll
        for (int h = 0; h < 32; h++)
            acc += x[h]*bf2f(wr[h*32]);
        atomicAdd(&neigh[(size_t)d*32 + o], acc);
    }
}

// m = relu(neigh*invdeg + out + cb); out_new = [m,out] @ mw + mb   (fp32)
__global__ void k_node(const float* __restrict__ neigh, const float* __restrict__ invdeg,
                       const float* __restrict__ outc, const float* __restrict__ cb,
                       const float* __restrict__ mw, const float* __restrict__ mb,
                       float* __restrict__ outn, int n)
{
    __shared__ float mwl[2048];
    __shared__ float cat[8][64];
    int tid = threadIdx.x;
    for (int i = tid; i < 2048; i += 256) mwl[i] = mw[i];
    int slot = tid>>5, o = tid&31;
    int v = blockIdx.x*8 + slot;
    if (v < n){
        float ov = outc[(size_t)v*32 + o];
        float m = neigh[(size_t)v*32 + o]*invdeg[v] + ov + cb[o];
        m = m > 0.f ? m : 0.f;
        cat[slot][o] = m;
        cat[slot][32+o] = ov;
    }
    __syncthreads();
    if (v < n){
        float a = mb[o];
        #pragma unroll
        for (int j = 0; j < 64; j++) a += cat[slot][j]*mwl[j*32+o];
        outn[(size_t)v*32 + o] = a;
    }
}

__global__ void k_group(const float* __restrict__ outc, const int* __restrict__ src,
                        const int* __restrict__ dst, float* __restrict__ grp, int E)
{
    int tid = threadIdx.x, slot = tid>>5, o = tid&31;
    int e = blockIdx.x*8 + slot;
    if (e < E)
        atomicAdd(&grp[(size_t)dst[e]*32 + o], outc[(size_t)src[e]*32 + o]);
}

// out_final = [out, group*invdeg] @ sw + sb + init  (fp32 out)
__global__ void k_final(const float* __restrict__ outc, const float* __restrict__ grp,
                        const float* __restrict__ invdeg, const float* __restrict__ sw,
                        const float* __restrict__ sb, const float* __restrict__ nfeat,
                        const float* __restrict__ rw,
                        float* __restrict__ dout, int n)
{
    __shared__ float swl[2048];
    __shared__ float cat[8][64];
    int tid = threadIdx.x;
    for (int i = tid; i < 2048; i += 256) swl[i] = sw[i];
    int slot = tid>>5, o = tid&31;
    int v = blockIdx.x*8 + slot;
    float iv = 0.f;
    if (v < n){
        iv = invdeg[v];
        cat[slot][o] = outc[(size_t)v*32 + o];
        cat[slot][32+o] = grp[(size_t)v*32 + o]*iv;
    }
    __syncthreads();
    if (v < n){
        float a = sb[o];
        #pragma unroll
        for (int j = 0; j < 64; j++) a += cat[slot][j]*swl[j*32+o];
        float initv = (o < 16) ? nfeat[(size_t)v*16 + o]
                               : rw[(size_t)(o-16)*n + v]*iv;
        dout[(size_t)v*32 + o] = a + initv;
    }
}

extern "C" void kernel_launch(void* const* d_in, const int* in_sizes, int n_in,
                              void* d_out, int out_size, void* d_ws, size_t ws_size,
                              hipStream_t stream)
{
    const float* n_feat = (const float*)d_in[0];
    const float* e_feat = (const float*)d_in[1];
    const int*   src    = (const int*)d_in[2];
    const int*   dst    = (const int*)d_in[3];
    const float* epw    = (const float*)d_in[4];
    const float* epb    = (const float*)d_in[5];
    const float* gw     = (const float*)d_in[6];
    const float* gb     = (const float*)d_in[7];
    const float* l0w    = (const float*)d_in[8];
    const float* l0b    = (const float*)d_in[9];
    const float* cb     = (const float*)d_in[10];
    const float* mw     = (const float*)d_in[11];
    const float* mbp    = (const float*)d_in[12];
    const float* sw     = (const float*)d_in[13];
    const float* sb     = (const float*)d_in[14];

    const int N = in_sizes[0] / 16;
    const int E = in_sizes[2];

    char* w = (char*)d_ws;
    float* invdeg = (float*)w;  w += (size_t)N*4;
    float* rw     = (float*)w;  w += (size_t)16*N*4;
    float* out_a  = (float*)w;  w += (size_t)32*N*4;
    float* out_b  = (float*)w;  w += (size_t)32*N*4;
    float* neigh  = (float*)w;  w += (size_t)32*N*4;
    u16*   wtb    = (u16*)w;    w += (size_t)1024*1024*2;
    u16*   abf    = (u16*)w;    w += (size_t)E*1024*2;
    float* gatev  = (float*)w;  w += (size_t)E*4;
    u16*   wout   = (u16*)w;

    hipMemsetAsync(invdeg, 0, (size_t)N*4, stream);
    hipMemsetAsync(rw, 0, (size_t)16*N*4, stream);

    const int EB  = (E + 255)/256, NB = (N + 255)/256;
    const int EB8 = (E + 7)/8,    NB8 = (N + 7)/8;

    k_deg<<<EB,256,0,stream>>>(dst, invdeg, E);
    k_degc<<<NB,256,0,stream>>>(invdeg, rw, N);
    for (int t = 0; t < 15; t++)
        k_rwse<<<EB,256,0,stream>>>(rw + (size_t)t*N, rw + (size_t)(t+1)*N, invdeg, src, dst, E);
    k_finalize<<<NB8,256,0,stream>>>(n_feat, rw, invdeg, l0w, l0b, out_a, N);

    k_transpose<<<1024,256,0,stream>>>(epw, wtb);
    k_prep<<<(E+3)/4,256,0,stream>>>(e_feat, gw, gb, abf, gatev, E);

    const int MBtot = (E + 127)/128;
    const int grid  = ((MBtot + 7)/8)*64;
    k_gemm<<<grid,256,0,stream>>>(abf, wtb, epb, gatev, wout, E);

    float* cur = out_a; float* nxt = out_b;
    for (int it = 0; it < 3; it++){
        hipMemsetAsync(neigh, 0, (size_t)32*N*4, stream);
        k_msg<<<EB8,256,0,stream>>>(cur, wout, src, dst, neigh, E);
        k_node<<<NB8,256,0,stream>>>(neigh, invdeg, cur, cb, mw, mbp, nxt, N);
        float* tmp = cur; cur = nxt; nxt = tmp;
    }

    hipMemsetAsync(neigh, 0, (size_t)32*N*4, stream);
    k_group<<<EB8,256,0,stream>>>(cur, src, dst, neigh, E);
    k_final<<<NB8,256,0,stream>>>(cur, neigh, invdeg, sw, sb, n_feat, rw, (float*)d_out, N);

    (void)n_in; (void)out_size; (void)ws_size;
}

// Round 2
// 1414.636 us; speedup vs baseline: 1.2049x; 1.0040x over previous
//
#include <hip/hip_runtime.h>
#include <hip/hip_bf16.h>

typedef unsigned short u16;
typedef unsigned int   u32;
typedef __bf16 bf16x8 __attribute__((ext_vector_type(8)));
typedef float  f32x4  __attribute__((ext_vector_type(4)));

#define AS1 __attribute__((address_space(1)))
#define AS3 __attribute__((address_space(3)))

__device__ __forceinline__ u16 f2bf(float f){
    u32 u = __float_as_uint(f);
    u32 r = u + 0x7fffu + ((u>>16)&1u);
    return (u16)(r>>16);
}
__device__ __forceinline__ float bf2f(u16 u){ return __uint_as_float(((u32)u)<<16); }

// ---------------- degree ----------------
__global__ void k_deg(const int* __restrict__ dst, float* __restrict__ degb, int E){
    int e = blockIdx.x*256 + threadIdx.x;
    if (e < E) atomicAdd(&degb[dst[e]], 1.0f);
}

// degb -> invdeg in place; rw0 = degc^2 (so rw0*invdeg = degc = RWSE col 0)
__global__ void k_degc(float* __restrict__ invdeg, float* __restrict__ rw0, int n){
    int v = blockIdx.x*256 + threadIdx.x;
    if (v < n){
        float c = invdeg[v];
        if (c == 0.f) c = 1.f;
        invdeg[v] = 1.f/c;
        rw0[v] = c*c;
    }
}

// raw_{t+1}[dst] += (raw_t[src] * invdeg[src])
__global__ void k_rwse(const float* __restrict__ cur, float* __restrict__ nxt,
                       const float* __restrict__ invdeg, const int* __restrict__ src,
                       const int* __restrict__ dst, int E){
    int e = blockIdx.x*256 + threadIdx.x;
    if (e < E){
        int s = src[e];
        atomicAdd(&nxt[dst[e]], cur[s]*invdeg[s]);
    }
}

// out0 = relu([n_feat, rwse] @ lin0_w + lin0_b)   (fp32)
__global__ void k_finalize(const float* __restrict__ nfeat, const float* __restrict__ rw,
                           const float* __restrict__ invdeg,
                           const float* __restrict__ lw, const float* __restrict__ lb,
                           float* __restrict__ out0, int n){
    __shared__ float lwl[1024];
    __shared__ float lbl[32];
    __shared__ float nfl[8][32];
    int tid = threadIdx.x;
    for (int i = tid; i < 1024; i += 256) lwl[i] = lw[i];
    if (tid < 32) lbl[tid] = lb[tid];
    int slot = tid>>5, o = tid&31;
    int v = blockIdx.x*8 + slot;
    float nfv = 0.f;
    if (v < n){
        nfv = (o < 16) ? nfeat[(size_t)v*16 + o]
                       : rw[(size_t)(o-16)*n + v]*invdeg[v];
    }
    nfl[slot][o] = nfv;
    __syncthreads();
    if (v < n){
        float a = lbl[o];
        #pragma unroll
        for (int j = 0; j < 32; j++) a += nfl[slot][j]*lwl[j*32+o];
        out0[(size_t)v*32 + o] = a > 0.f ? a : 0.f;
    }
}

// WT[n*1024+k] = bf16(w[k*1024+n])  (fp32 -> bf16, 1024x1024)
__global__ void k_transpose(const float* __restrict__ w, u16* __restrict__ wt){
    __shared__ float t[32][33];
    int bx = blockIdx.x & 31, by = blockIdx.x >> 5;
    int x = threadIdx.x & 31, y = threadIdx.x >> 5;
    #pragma unroll
    for (int i = 0; i < 32; i += 8)
        t[y+i][x] = w[(size_t)(by*32 + y + i)*1024 + bx*32 + x];
    __syncthreads();
    #pragma unroll
    for (int i = 0; i < 32; i += 8)
        wt[(size_t)(bx*32 + y + i)*1024 + by*32 + x] = f2bf(t[x][y+i]);
}

// Pre-pass: A fp32 -> bf16 (rounded), plus gate[e] = sigmoid(A[e,:] . gw + gb) in fp32.
__global__ __launch_bounds__(256) void k_prep(
    const float* __restrict__ A, const float* __restrict__ gw,
    const float* __restrict__ gb, u16* __restrict__ Abf,
    float* __restrict__ gate, int E)
{
    __shared__ f32x4 gwl[256];
    const int tid = threadIdx.x;
    const int wave = tid>>6, lane = tid&63;
    gwl[tid] = ((const f32x4*)gw)[tid];
    __syncthreads();
    const int row = blockIdx.x*4 + wave;
    if (row >= E) return;
    const f32x4* ar = (const f32x4*)(A + (size_t)row*1024);
    ushort4* br = (ushort4*)(Abf + (size_t)row*1024);
    float g = 0.f;
    #pragma unroll
    for (int j = 0; j < 4; j++){
        const int idx = j*64 + lane;
        f32x4 v = ar[idx];
        f32x4 w4 = gwl[idx];
        g += v.x*w4.x + v.y*w4.y + v.z*w4.z + v.w*w4.w;
        ushort4 o;
        o.x = f2bf(v.x); o.y = f2bf(v.y); o.z = f2bf(v.z); o.w = f2bf(v.w);
        br[idx] = o;
    }
    #pragma unroll
    for (int m = 32; m >= 1; m >>= 1) g += __shfl_xor(g, m);
    if (lane == 0) gate[row] = 1.f/(1.f + __expf(-(g + gb[0])));
}

// W = relu(A @ B + bias) * gate, natural row-major store [h*32+o].
// 3-deep circular LDS buffer, counted vmcnt(4), raw s_barrier (one per K-step):
// stage tile t+2 while computing tile t -> load latency spans 2 compute phases.
__global__ __launch_bounds__(256) void k_gemm(
    const u16* __restrict__ A, const u16* __restrict__ BT,
    const float* __restrict__ bias, const float* __restrict__ gate,
    u16* __restrict__ Wout, int E)
{
    __shared__ __align__(16) u16 lds_a[3*128*32];  // 3 bufs x [q][m] chunks of 8 bf16
    __shared__ __align__(16) u16 lds_b[3*128*32];  // 3 bufs x [q][n] chunks of 8 bf16
    __shared__ float gate_lds[128];
    __shared__ float bias_lds[128];

    const int tid  = threadIdx.x;
    const int wave = tid>>6, lane = tid&63;
    const int wm = wave>>1, wn = wave&1;
    const int ql = lane>>4, rl = lane&15;

    // swizzle: 8 nb-siblings of a row panel sit at ids == same value mod 8
    const int id  = blockIdx.x;
    const int xcd = id & 7;
    const int s   = id >> 3;
    const int nb  = s & 7;
    const int mb  = (s >> 3)*8 + xcd;
    const int MBtot = (E + 127) >> 7;
    if (mb >= MBtot) return;
    const int m0 = mb<<7, n0 = nb<<7;

    if (tid < 128){
        const int row = m0 + tid;
        gate_lds[tid] = gate[row < E ? row : E-1];
    } else {
        bias_lds[tid-128] = bias[n0 + tid - 128];
    }
    __syncthreads();   // orders gate/bias LDS writes; nothing else in flight yet

#define STAGE(buf, kk)                                                      \
    {                                                                       \
        const int k0s = (kk);                                               \
        _Pragma("unroll")                                                   \
        for (int j=0;j<2;j++){                                              \
            const int cb = (j*4 + wave)*64;                                 \
            const int ci = cb + lane;                                       \
            const int m  = ci & 127, q = ci >> 7;                           \
            int row = m0 + m; if (row >= E) row = E-1;                      \
            const u16* ga = A + (size_t)row*1024 + k0s + q*8;               \
            __builtin_amdgcn_global_load_lds((const AS1 void*)ga,           \
                (AS3 void*)&lds_a[(buf)*4096 + ci*8], 16, 0, 0);            \
            const u16* gB = BT + (size_t)(n0 + m)*1024 + (k0s + q*8);       \
            __builtin_amdgcn_global_load_lds((const AS1 void*)gB,           \
                (AS3 void*)&lds_b[(buf)*4096 + ci*8], 16, 0, 0);            \
        }                                                                   \
    }

    f32x4 acc[4][4];
    #pragma unroll
    for (int i=0;i<4;i++)
    #pragma unroll
        for (int j=0;j<4;j++) acc[i][j] = (f32x4){0.f,0.f,0.f,0.f};

    // prologue: fill buffers 0 and 1 (8 loads/thread outstanding)
    STAGE(0, 0)
    STAGE(1, 32)
    asm volatile("s_waitcnt vmcnt(4)" ::: "memory");   // buf0 landed (4 newest = buf1)
    __builtin_amdgcn_s_barrier();

    int bc = 0;                       // compute-buffer index for iter t
    for (int t = 0; t < 32; ++t){
        if (t + 2 < 32){
            int bs = bc + 2; if (bs >= 3) bs -= 3;
            STAGE(bs, (t+2)*32)
        }

        const u16* la = &lds_a[bc*4096];
        const u16* lb = &lds_b[bc*4096];
        bf16x8 af[4], bfr[4];
        #pragma unroll
        for (int tt=0;tt<4;tt++){
            af[tt]  = *(const bf16x8*)&la[(ql*128 + wm*64 + tt*16 + rl)*8];
            bfr[tt] = *(const bf16x8*)&lb[(ql*128 + wn*64 + tt*16 + rl)*8];
        }
        #pragma unroll
        for (int mt=0;mt<4;mt++)
        #pragma unroll
            for (int nt=0;nt<4;nt++)
                acc[mt][nt] = __builtin_amdgcn_mfma_f32_16x16x32_bf16(af[mt], bfr[nt], acc[mt][nt], 0,0,0);

        // end-of-iter: guarantee buf[t+1] landed before next iter reads it.
        // steady state: outstanding = stage(t+1) [oldest 4] + stage(t+2) [newest 4]
        if (t + 2 < 32)      asm volatile("s_waitcnt vmcnt(4)" ::: "memory");
        else if (t + 1 < 32) asm volatile("s_waitcnt vmcnt(0)" ::: "memory");
        if (t + 1 < 32) __builtin_amdgcn_s_barrier();

        bc = bc + 1; if (bc >= 3) bc -= 3;
    }
#undef STAGE

    float bcol[4];
    #pragma unroll
    for (int nt=0;nt<4;nt++) bcol[nt] = bias_lds[wn*64 + nt*16 + rl];

    #pragma unroll
    for (int mt=0;mt<4;mt++){
        const int rloc0 = wm*64 + mt*16 + ql*4;
        #pragma unroll
        for (int r=0;r<4;r++){
            const int row = m0 + rloc0 + r;
            if (row < E){
                const float g = gate_lds[rloc0 + r];
                u16* wrow = Wout + (size_t)row*1024 + n0 + wn*64 + rl;
                #pragma unroll
                for (int nt=0;nt<4;nt++){    // consecutive nt -> adjacent 32B runs, write-combine
                    float v = acc[mt][nt][r] + bcol[nt];
                    v = v > 0.f ? v : 0.f;
                    wrow[nt*16] = f2bf(v*g);
                }
            }
        }
    }
}

// msg[e][o] = sum_h out[src[e]][h] * W[e, h*32+o]; atomic into neigh[dst]
__global__ void k_msg(const float* __restrict__ outc, const u16* __restrict__ W,
                      const int* __restrict__ src, const int* __restrict__ dst,
                      float* __restrict__ neigh, int E)
{
    __shared__ float xl[8][32];
    const int tid = threadIdx.x, slot = tid>>5, o = tid&31;
    const int e = blockIdx.x*8 + slot;
    int d = 0;
    if (e < E){
        d = dst[e];
        xl[slot][o] = outc[(size_t)src[e]*32 + o];
    }
    __syncthreads();
    if (e < E){
        const float* x = xl[slot];
        const u16* wr = W + (size_t)e*1024 + o;
        float acc = 0.f;
        #pragma unroll
        for (int h = 0; h < 32; h++)
            acc += x[h]*bf2f(wr[h*32]);
        atomicAdd(&neigh[(size_t)d*32 + o], acc);
    }
}

// m = relu(neigh*invdeg + out + cb); out_new = [m,out] @ mw + mb   (fp32)
__global__ void k_node(const float* __restrict__ neigh, const float* __restrict__ invdeg,
                       const float* __restrict__ outc, const float* __restrict__ cb,
                       const float* __restrict__ mw, const float* __restrict__ mb,
                       float* __restrict__ outn, int n)
{
    __shared__ float mwl[2048];
    __shared__ float cat[8][64];
    int tid = threadIdx.x;
    for (int i = tid; i < 2048; i += 256) mwl[i] = mw[i];
    int slot = tid>>5, o = tid&31;
    int v = blockIdx.x*8 + slot;
    if (v < n){
        float ov = outc[(size_t)v*32 + o];
        float m = neigh[(size_t)v*32 + o]*invdeg[v] + ov + cb[o];
        m = m > 0.f ? m : 0.f;
        cat[slot][o] = m;
        cat[slot][32+o] = ov;
    }
    __syncthreads();
    if (v < n){
        float a = mb[o];
        #pragma unroll
        for (int j = 0; j < 64; j++) a += cat[slot][j]*mwl[j*32+o];
        outn[(size_t)v*32 + o] = a;
    }
}

__global__ void k_group(const float* __restrict__ outc, const int* __restrict__ src,
                        const int* __restrict__ dst, float* __restrict__ grp, int E)
{
    int tid = threadIdx.x, slot = tid>>5, o = tid&31;
    int e = blockIdx.x*8 + slot;
    if (e < E)
        atomicAdd(&grp[(size_t)dst[e]*32 + o], outc[(size_t)src[e]*32 + o]);
}

// out_final = [out, group*invdeg] @ sw + sb + init  (fp32 out)
__global__ void k_final(const float* __restrict__ outc, const float* __restrict__ grp,
                        const float* __restrict__ invdeg, const float* __restrict__ sw,
                        const float* __restrict__ sb, const float* __restrict__ nfeat,
                        const float* __restrict__ rw,
                        float* __restrict__ dout, int n)
{
    __shared__ float swl[2048];
    __shared__ float cat[8][64];
    int tid = threadIdx.x;
    for (int i = tid; i < 2048; i += 256) swl[i] = sw[i];
    int slot = tid>>5, o = tid&31;
    int v = blockIdx.x*8 + slot;
    float iv = 0.f;
    if (v < n){
        iv = invdeg[v];
        cat[slot][o] = outc[(size_t)v*32 + o];
        cat[slot][32+o] = grp[(size_t)v*32 + o]*iv;
    }
    __syncthreads();
    if (v < n){
        float a = sb[o];
        #pragma unroll
        for (int j = 0; j < 64; j++) a += cat[slot][j]*swl[j*32+o];
        float initv = (o < 16) ? nfeat[(size_t)v*16 + o]
                               : rw[(size_t)(o-16)*n + v]*iv;
        dout[(size_t)v*32 + o] = a + initv;
    }
}

extern "C" void kernel_launch(void* const* d_in, const int* in_sizes, int n_in,
                              void* d_out, int out_size, void* d_ws, size_t ws_size,
                              hipStream_t stream)
{
    const float* n_feat = (const float*)d_in[0];
    const float* e_feat = (const float*)d_in[1];
    const int*   src    = (const int*)d_in[2];
    const int*   dst    = (const int*)d_in[3];
    const float* epw    = (const float*)d_in[4];
    const float* epb    = (const float*)d_in[5];
    const float* gw     = (const float*)d_in[6];
    const float* gb     = (const float*)d_in[7];
    const float* l0w    = (const float*)d_in[8];
    const float* l0b    = (const float*)d_in[9];
    const float* cb     = (const float*)d_in[10];
    const float* mw     = (const float*)d_in[11];
    const float* mbp    = (const float*)d_in[12];
    const float* sw     = (const float*)d_in[13];
    const float* sb     = (const float*)d_in[14];

    const int N = in_sizes[0] / 16;
    const int E = in_sizes[2];

    char* w = (char*)d_ws;
    float* invdeg = (float*)w;  w += (size_t)N*4;
    float* rw     = (float*)w;  w += (size_t)16*N*4;
    float* out_a  = (float*)w;  w += (size_t)32*N*4;
    float* out_b  = (float*)w;  w += (size_t)32*N*4;
    float* neigh  = (float*)w;  w += (size_t)32*N*4;
    u16*   wtb    = (u16*)w;    w += (size_t)1024*1024*2;
    u16*   abf    = (u16*)w;    w += (size_t)E*1024*2;
    float* gatev  = (float*)w;  w += (size_t)E*4;
    u16*   wout   = (u16*)w;

    hipMemsetAsync(invdeg, 0, (size_t)N*4, stream);
    hipMemsetAsync(rw, 0, (size_t)16*N*4, stream);

    const int EB  = (E + 255)/256, NB = (N + 255)/256;
    const int EB8 = (E + 7)/8,    NB8 = (N + 7)/8;

    k_deg<<<EB,256,0,stream>>>(dst, invdeg, E);
    k_degc<<<NB,256,0,stream>>>(invdeg, rw, N);
    for (int t = 0; t < 15; t++)
        k_rwse<<<EB,256,0,stream>>>(rw + (size_t)t*N, rw + (size_t)(t+1)*N, invdeg, src, dst, E);
    k_finalize<<<NB8,256,0,stream>>>(n_feat, rw, invdeg, l0w, l0b, out_a, N);

    k_transpose<<<1024,256,0,stream>>>(epw, wtb);
    k_prep<<<(E+3)/4,256,0,stream>>>(e_feat, gw, gb, abf, gatev, E);

    const int MBtot = (E + 127)/128;
    const int grid  = ((MBtot + 7)/8)*64;
    k_gemm<<<grid,256,0,stream>>>(abf, wtb, epb, gatev, wout, E);

    float* cur = out_a; float* nxt = out_b;
    for (int it = 0; it < 3; it++){
        hipMemsetAsync(neigh, 0, (size_t)32*N*4, stream);
        k_msg<<<EB8,256,0,stream>>>(cur, wout, src, dst, neigh, E);
        k_node<<<NB8,256,0,stream>>>(neigh, invdeg, cur, cb, mw, mbp, nxt, N);
        float* tmp = cur; cur = nxt; nxt = tmp;
    }

    hipMemsetAsync(neigh, 0, (size_t)32*N*4, stream);
    k_group<<<EB8,256,0,stream>>>(cur, src, dst, neigh, E);
    k_final<<<NB8,256,0,stream>>>(cur, neigh, invdeg, sw, sb, n_feat, rw, (float*)d_out, N);

    (void)n_in; (void)out_size; (void)ws_size;
}

// Round 3
// 1263.986 us; speedup vs baseline: 1.3485x; 1.1192x over previous
//
#include <hip/hip_runtime.h>
#include <hip/hip_bf16.h>

typedef unsigned short u16;
typedef unsigned int   u32;
typedef __bf16 bf16x8 __attribute__((ext_vector_type(8)));
typedef float  f32x4  __attribute__((ext_vector_type(4)));

#define AS1 __attribute__((address_space(1)))
#define AS3 __attribute__((address_space(3)))

__device__ __forceinline__ u16 f2bf(float f){
    u32 u = __float_as_uint(f);
    u32 r = u + 0x7fffu + ((u>>16)&1u);
    return (u16)(r>>16);
}
__device__ __forceinline__ float bf2f(u16 u){ return __uint_as_float(((u32)u)<<16); }

// ---------------- degree ----------------
__global__ void k_deg(const int* __restrict__ dst, float* __restrict__ degb, int E){
    int e = blockIdx.x*256 + threadIdx.x;
    if (e < E) atomicAdd(&degb[dst[e]], 1.0f);
}

// degb -> invdeg in place; rw0 = degc^2 (so rw0*invdeg = degc = RWSE col 0)
__global__ void k_degc(float* __restrict__ invdeg, float* __restrict__ rw0, int n){
    int v = blockIdx.x*256 + threadIdx.x;
    if (v < n){
        float c = invdeg[v];
        if (c == 0.f) c = 1.f;
        invdeg[v] = 1.f/c;
        rw0[v] = c*c;
    }
}

// raw_{t+1}[dst] += (raw_t[src] * invdeg[src])
__global__ void k_rwse(const float* __restrict__ cur, float* __restrict__ nxt,
                       const float* __restrict__ invdeg, const int* __restrict__ src,
                       const int* __restrict__ dst, int E){
    int e = blockIdx.x*256 + threadIdx.x;
    if (e < E){
        int s = src[e];
        atomicAdd(&nxt[dst[e]], cur[s]*invdeg[s]);
    }
}

// out0 = relu([n_feat, rwse] @ lin0_w + lin0_b)   (fp32)
__global__ void k_finalize(const float* __restrict__ nfeat, const float* __restrict__ rw,
                           const float* __restrict__ invdeg,
                           const float* __restrict__ lw, const float* __restrict__ lb,
                           float* __restrict__ out0, int n){
    __shared__ float lwl[1024];
    __shared__ float lbl[32];
    __shared__ float nfl[8][32];
    int tid = threadIdx.x;
    for (int i = tid; i < 1024; i += 256) lwl[i] = lw[i];
    if (tid < 32) lbl[tid] = lb[tid];
    int slot = tid>>5, o = tid&31;
    int v = blockIdx.x*8 + slot;
    float nfv = 0.f;
    if (v < n){
        nfv = (o < 16) ? nfeat[(size_t)v*16 + o]
                       : rw[(size_t)(o-16)*n + v]*invdeg[v];
    }
    nfl[slot][o] = nfv;
    __syncthreads();
    if (v < n){
        float a = lbl[o];
        #pragma unroll
        for (int j = 0; j < 32; j++) a += nfl[slot][j]*lwl[j*32+o];
        out0[(size_t)v*32 + o] = a > 0.f ? a : 0.f;
    }
}

// WT[n*1024+k] = bf16(w[k*1024+n])  (fp32 -> bf16, 1024x1024)
__global__ void k_transpose(const float* __restrict__ w, u16* __restrict__ wt){
    __shared__ float t[32][33];
    int bx = blockIdx.x & 31, by = blockIdx.x >> 5;
    int x = threadIdx.x & 31, y = threadIdx.x >> 5;
    #pragma unroll
    for (int i = 0; i < 32; i += 8)
        t[y+i][x] = w[(size_t)(by*32 + y + i)*1024 + bx*32 + x];
    __syncthreads();
    #pragma unroll
    for (int i = 0; i < 32; i += 8)
        wt[(size_t)(bx*32 + y + i)*1024 + by*32 + x] = f2bf(t[x][y+i]);
}

// Pre-pass: A fp32 -> bf16 (rounded), plus gate[e] = sigmoid(A[e,:] . gw + gb) in fp32.
__global__ __launch_bounds__(256) void k_prep(
    const float* __restrict__ A, const float* __restrict__ gw,
    const float* __restrict__ gb, u16* __restrict__ Abf,
    float* __restrict__ gate, int E)
{
    __shared__ f32x4 gwl[256];
    const int tid = threadIdx.x;
    const int wave = tid>>6, lane = tid&63;
    gwl[tid] = ((const f32x4*)gw)[tid];
    __syncthreads();
    const int row = blockIdx.x*4 + wave;
    if (row >= E) return;
    const f32x4* ar = (const f32x4*)(A + (size_t)row*1024);
    ushort4* br = (ushort4*)(Abf + (size_t)row*1024);
    float g = 0.f;
    #pragma unroll
    for (int j = 0; j < 4; j++){
        const int idx = j*64 + lane;
        f32x4 v = ar[idx];
        f32x4 w4 = gwl[idx];
        g += v.x*w4.x + v.y*w4.y + v.z*w4.z + v.w*w4.w;
        ushort4 o;
        o.x = f2bf(v.x); o.y = f2bf(v.y); o.z = f2bf(v.z); o.w = f2bf(v.w);
        br[idx] = o;
    }
    #pragma unroll
    for (int m = 32; m >= 1; m >>= 1) g += __shfl_xor(g, m);
    if (lane == 0) gate[row] = 1.f/(1.f + __expf(-(g + gb[0])));
}

// W = relu(A @ B + bias) * gate, natural row-major store [h*32+o].
// Row-contiguous staging: one global_load_lds = 16 rows x 64B full lines
// (16 cache-line requests vs 64 scattered 16B) -> 4x fewer VMEM requests.
// LDS tile layout [m][chunk], chunk XOR-swizzled with (m>>1)&3 on BOTH the
// global source k-offset and the fragment ds_read (both-sides rule).
// 3-deep circular buffer, counted vmcnt(4), one raw barrier per K-step.
__global__ __launch_bounds__(256) void k_gemm(
    const u16* __restrict__ A, const u16* __restrict__ BT,
    const float* __restrict__ bias, const float* __restrict__ gate,
    u16* __restrict__ Wout, int E)
{
    __shared__ __align__(16) u16 lds_a[3*128*32];  // 3 bufs x [m=128][c=4][8]
    __shared__ __align__(16) u16 lds_b[3*128*32];  // 3 bufs x [n=128][c=4][8]
    __shared__ float gate_lds[128];
    __shared__ float bias_lds[128];

    const int tid  = threadIdx.x;
    const int wave = tid>>6, lane = tid&63;
    const int wm = wave>>1, wn = wave&1;
    const int ql = lane>>4, rl = lane&15;

    // swizzle: 8 nb-siblings of a row panel sit at ids == same value mod 8
    const int id  = blockIdx.x;
    const int xcd = id & 7;
    const int s   = id >> 3;
    const int nb  = s & 7;
    const int mb  = (s >> 3)*8 + xcd;
    const int MBtot = (E + 127) >> 7;
    if (mb >= MBtot) return;
    const int m0 = mb<<7, n0 = nb<<7;

    if (tid < 128){
        const int row = m0 + tid;
        gate_lds[tid] = gate[row < E ? row : E-1];
    } else {
        bias_lds[tid-128] = bias[n0 + tid - 128];
    }
    __syncthreads();   // orders gate/bias LDS writes; nothing else in flight yet

    // ---- staging pointers (hoisted; advance 32 elems per K-step) ----
    // inst j covers ci = (j*4+wave)*64 + lane; m|n = ci>>2, c = ci&3,
    // source k-chunk q = c ^ ((m>>1)&3)  (inverse swizzle pre-applied)
    const int ci0 = (0*4 + wave)*64 + lane;
    const int ci1 = (1*4 + wave)*64 + lane;
    const int mA0 = ci0>>2, cA0 = ci0&3, qA0 = cA0 ^ ((mA0>>1)&3);
    const int mA1 = ci1>>2, cA1 = ci1&3, qA1 = cA1 ^ ((mA1>>1)&3);
    int rA0 = m0 + mA0; if (rA0 >= E) rA0 = E-1;
    int rA1 = m0 + mA1; if (rA1 >= E) rA1 = E-1;
    const u16* pA0 = A + (size_t)rA0*1024 + qA0*8;
    const u16* pA1 = A + (size_t)rA1*1024 + qA1*8;
    const u16* pB0 = BT + (size_t)(n0 + mA0)*1024 + qA0*8;
    const u16* pB1 = BT + (size_t)(n0 + mA1)*1024 + qA1*8;
    // wave-uniform LDS chunk bases (lane*16B added by HW)
    const int cb0 = (0*4 + wave)*64;
    const int cb1 = (1*4 + wave)*64;

#define STAGE(buf)                                                          \
    {                                                                       \
        __builtin_amdgcn_global_load_lds((const AS1 void*)pA0,              \
            (AS3 void*)&lds_a[(buf)*4096 + cb0*8], 16, 0, 0);               \
        __builtin_amdgcn_global_load_lds((const AS1 void*)pB0,              \
            (AS3 void*)&lds_b[(buf)*4096 + cb0*8], 16, 0, 0);               \
        __builtin_amdgcn_global_load_lds((const AS1 void*)pA1,              \
            (AS3 void*)&lds_a[(buf)*4096 + cb1*8], 16, 0, 0);               \
        __builtin_amdgcn_global_load_lds((const AS1 void*)pB1,              \
            (AS3 void*)&lds_b[(buf)*4096 + cb1*8], 16, 0, 0);               \
        pA0 += 32; pA1 += 32; pB0 += 32; pB1 += 32;                         \
    }

    // fragment read offsets (u16 units): row-major [m][c] with XOR'd chunk;
    // (m>>1)&3 == (rl>>1)&3 for all t (t*16 and wm*64 add multiples of 8)
    const int xr = (rl>>1)&3;
    const int a_off = (wm*64 + rl)*32 + (ql ^ xr)*8;
    const int b_off = (wn*64 + rl)*32 + (ql ^ xr)*8;

    f32x4 acc[4][4];
    #pragma unroll
    for (int i=0;i<4;i++)
    #pragma unroll
        for (int j=0;j<4;j++) acc[i][j] = (f32x4){0.f,0.f,0.f,0.f};

    // prologue: fill buffers 0 and 1 (8 loads/thread outstanding)
    STAGE(0)
    STAGE(1)
    asm volatile("s_waitcnt vmcnt(4)" ::: "memory");   // buf0 landed (4 newest = buf1)
    __builtin_amdgcn_s_barrier();

    int bc = 0;                       // compute-buffer index for iter t
    for (int t = 0; t < 32; ++t){
        if (t + 2 < 32){
            int bs = bc + 2; if (bs >= 3) bs -= 3;
            STAGE(bs)
        }

        const u16* la = &lds_a[bc*4096];
        const u16* lb = &lds_b[bc*4096];
        bf16x8 af[4], bfr[4];
        #pragma unroll
        for (int tt=0;tt<4;tt++){
            af[tt]  = *(const bf16x8*)&la[a_off + tt*512];
            bfr[tt] = *(const bf16x8*)&lb[b_off + tt*512];
        }
        #pragma unroll
        for (int mt=0;mt<4;mt++)
        #pragma unroll
            for (int nt=0;nt<4;nt++)
                acc[mt][nt] = __builtin_amdgcn_mfma_f32_16x16x32_bf16(af[mt], bfr[nt], acc[mt][nt], 0,0,0);

        // end-of-iter: guarantee buf[t+1] landed before next iter reads it.
        // steady state: outstanding = stage(t+1) [oldest 4] + stage(t+2) [newest 4]
        if (t + 2 < 32)      asm volatile("s_waitcnt vmcnt(4)" ::: "memory");
        else if (t + 1 < 32) asm volatile("s_waitcnt vmcnt(0)" ::: "memory");
        if (t + 1 < 32) __builtin_amdgcn_s_barrier();

        bc = bc + 1; if (bc >= 3) bc -= 3;
    }
#undef STAGE

    float bcol[4];
    #pragma unroll
    for (int nt=0;nt<4;nt++) bcol[nt] = bias_lds[wn*64 + nt*16 + rl];

    #pragma unroll
    for (int mt=0;mt<4;mt++){
        const int rloc0 = wm*64 + mt*16 + ql*4;
        #pragma unroll
        for (int r=0;r<4;r++){
            const int row = m0 + rloc0 + r;
            if (row < E){
                const float g = gate_lds[rloc0 + r];
                u16* wrow = Wout + (size_t)row*1024 + n0 + wn*64 + rl;
                #pragma unroll
                for (int nt=0;nt<4;nt++){    // consecutive nt -> adjacent 32B runs, write-combine
                    float v = acc[mt][nt][r] + bcol[nt];
                    v = v > 0.f ? v : 0.f;
                    wrow[nt*16] = f2bf(v*g);
                }
            }
        }
    }
}

// msg[e][o] = sum_h out[src[e]][h] * W[e, h*32+o]; atomic into neigh[dst]
__global__ void k_msg(const float* __restrict__ outc, const u16* __restrict__ W,
                      const int* __restrict__ src, const int* __restrict__ dst,
                      float* __restrict__ neigh, int E)
{
    __shared__ float xl[8][32];
    const int tid = threadIdx.x, slot = tid>>5, o = tid&31;
    const int e = blockIdx.x*8 + slot;
    int d = 0;
    if (e < E){
        d = dst[e];
        xl[slot][o] = outc[(size_t)src[e]*32 + o];
    }
    __syncthreads();
    if (e < E){
        const float* x = xl[slot];
        const u16* wr = W + (size_t)e*1024 + o;
        float acc = 0.f;
        #pragma unroll
        for (int h = 0; h < 32; h++)
            acc += x[h]*bf2f(wr[h*32]);
        atomicAdd(&neigh[(size_t)d*32 + o], acc);
    }
}

// m = relu(neigh*invdeg + out + cb); out_new = [m,out] @ mw + mb   (fp32)
__global__ void k_node(const float* __restrict__ neigh, const float* __restrict__ invdeg,
                       const float* __restrict__ outc, const float* __restrict__ cb,
                       const float* __restrict__ mw, const float* __restrict__ mb,
                       float* __restrict__ outn, int n)
{
    __shared__ float mwl[2048];
    __shared__ float cat[8][64];
    int tid = threadIdx.x;
    for (int i = tid; i < 2048; i += 256) mwl[i] = mw[i];
    int slot = tid>>5, o = tid&31;
    int v = blockIdx.x*8 + slot;
    if (v < n){
        float ov = outc[(size_t)v*32 + o];
        float m = neigh[(size_t)v*32 + o]*invdeg[v] + ov + cb[o];
        m = m > 0.f ? m : 0.f;
        cat[slot][o] = m;
        cat[slot][32+o] = ov;
    }
    __syncthreads();
    if (v < n){
        float a = mb[o];
        #pragma unroll
        for (int j = 0; j < 64; j++) a += cat[slot][j]*mwl[j*32+o];
        outn[(size_t)v*32 + o] = a;
    }
}

__global__ void k_group(const float* __restrict__ outc, const int* __restrict__ src,
                        const int* __restrict__ dst, float* __restrict__ grp, int E)
{
    int tid = threadIdx.x, slot = tid>>5, o = tid&31;
    int e = blockIdx.x*8 + slot;
    if (e < E)
        atomicAdd(&grp[(size_t)dst[e]*32 + o], outc[(size_t)src[e]*32 + o]);
}

// out_final = [out, group*invdeg] @ sw + sb + init  (fp32 out)
__global__ void k_final(const float* __restrict__ outc, const float* __restrict__ grp,
                        const float* __restrict__ invdeg, const float* __restrict__ sw,
                        const float* __restrict__ sb, const float* __restrict__ nfeat,
                        const float* __restrict__ rw,
                        float* __restrict__ dout, int n)
{
    __shared__ float swl[2048];
    __shared__ float cat[8][64];
    int tid = threadIdx.x;
    for (int i = tid; i < 2048; i += 256) swl[i] = sw[i];
    int slot = tid>>5, o = tid&31;
    int v = blockIdx.x*8 + slot;
    float iv = 0.f;
    if (v < n){
        iv = invdeg[v];
        cat[slot][o] = outc[(size_t)v*32 + o];
        cat[slot][32+o] = grp[(size_t)v*32 + o]*iv;
    }
    __syncthreads();
    if (v < n){
        float a = sb[o];
        #pragma unroll
        for (int j = 0; j < 64; j++) a += cat[slot][j]*swl[j*32+o];
        float initv = (o < 16) ? nfeat[(size_t)v*16 + o]
                               : rw[(size_t)(o-16)*n + v]*iv;
        dout[(size_t)v*32 + o] = a + initv;
    }
}

extern "C" void kernel_launch(void* const* d_in, const int* in_sizes, int n_in,
                              void* d_out, int out_size, void* d_ws, size_t ws_size,
                              hipStream_t stream)
{
    const float* n_feat = (const float*)d_in[0];
    const float* e_feat = (const float*)d_in[1];
    const int*   src    = (const int*)d_in[2];
    const int*   dst    = (const int*)d_in[3];
    const float* epw    = (const float*)d_in[4];
    const float* epb    = (const float*)d_in[5];
    const float* gw     = (const float*)d_in[6];
    const float* gb     = (const float*)d_in[7];
    const float* l0w    = (const float*)d_in[8];
    const float* l0b    = (const float*)d_in[9];
    const float* cb     = (const float*)d_in[10];
    const float* mw     = (const float*)d_in[11];
    const float* mbp    = (const float*)d_in[12];
    const float* sw     = (const float*)d_in[13];
    const float* sb     = (const float*)d_in[14];

    const int N = in_sizes[0] / 16;
    const int E = in_sizes[2];

    char* w = (char*)d_ws;
    float* invdeg = (float*)w;  w += (size_t)N*4;
    float* rw     = (float*)w;  w += (size_t)16*N*4;
    float* out_a  = (float*)w;  w += (size_t)32*N*4;
    float* out_b  = (float*)w;  w += (size_t)32*N*4;
    float* neigh  = (float*)w;  w += (size_t)32*N*4;
    u16*   wtb    = (u16*)w;    w += (size_t)1024*1024*2;
    u16*   abf    = (u16*)w;    w += (size_t)E*1024*2;
    float* gatev  = (float*)w;  w += (size_t)E*4;
    u16*   wout   = (u16*)w;

    hipMemsetAsync(invdeg, 0, (size_t)N*4, stream);
    hipMemsetAsync(rw, 0, (size_t)16*N*4, stream);

    const int EB  = (E + 255)/256, NB = (N + 255)/256;
    const int EB8 = (E + 7)/8,    NB8 = (N + 7)/8;

    k_deg<<<EB,256,0,stream>>>(dst, invdeg, E);
    k_degc<<<NB,256,0,stream>>>(invdeg, rw, N);
    for (int t = 0; t < 15; t++)
        k_rwse<<<EB,256,0,stream>>>(rw + (size_t)t*N, rw + (size_t)(t+1)*N, invdeg, src, dst, E);
    k_finalize<<<NB8,256,0,stream>>>(n_feat, rw, invdeg, l0w, l0b, out_a, N);

    k_transpose<<<1024,256,0,stream>>>(epw, wtb);
    k_prep<<<(E+3)/4,256,0,stream>>>(e_feat, gw, gb, abf, gatev, E);

    const int MBtot = (E + 127)/128;
    const int grid  = ((MBtot + 7)/8)*64;
    k_gemm<<<grid,256,0,stream>>>(abf, wtb, epb, gatev, wout, E);

    float* cur = out_a; float* nxt = out_b;
    for (int it = 0; it < 3; it++){
        hipMemsetAsync(neigh, 0, (size_t)32*N*4, stream);
        k_msg<<<EB8,256,0,stream>>>(cur, wout, src, dst, neigh, E);
        k_node<<<NB8,256,0,stream>>>(neigh, invdeg, cur, cb, mw, mbp, nxt, N);
        float* tmp = cur; cur = nxt; nxt = tmp;
    }

    hipMemsetAsync(neigh, 0, (size_t)32*N*4, stream);
    k_group<<<EB8,256,0,stream>>>(cur, src, dst, neigh, E);
    k_final<<<NB8,256,0,stream>>>(cur, neigh, invdeg, sw, sb, n_feat, rw, (float*)d_out, N);

    (void)n_in; (void)out_size; (void)ws_size;
}